// Round 1
// baseline (1367.699 us; speedup 1.0000x reference)
//
#include <hip/hip_runtime.h>
#include <math.h>

#define DIMX   1024
#define SDN    1024
#define BATCHN 2
#define LSEQ   2048
#define BLROWS (BATCHN*LSEQ)
#define NCHUNK 16
#define LCHUNK (LSEQ/NCHUNK)
#define PI_F   3.14159265358979f

__device__ __forceinline__ float softplusf_(float x) {
  return x > 20.0f ? x : log1pf(expf(x));
}

__device__ __forceinline__ float2 cfma2(float2 a, float2 v, float2 u) {
  // a*v + u (complex)
  float re = fmaf(a.x, v.x, fmaf(-a.y, v.y, u.x));
  float im = fmaf(a.x, v.y, fmaf(a.y, v.x, u.y));
  return make_float2(re, im);
}

// ---------------- coefficients: a = exp(lam*dt), A = a^LCHUNK ----------------
__global__ void coef_kernel(const float* __restrict__ omega,
                            const float* __restrict__ log_gamma,
                            const float* __restrict__ dt,
                            float2* __restrict__ a_out,
                            float2* __restrict__ A_out) {
  int s = blockIdx.x * blockDim.x + threadIdx.x;
  if (s >= SDN) return;
  double dtv = (double)dt[0];
  double dte = dtv > 20.0 ? dtv : log1p(exp(dtv));
  double gam = 0.0;
  if (s < SDN - SDN / 4) {  // not_unitary: band0 = indices [768,1023] (freqs strictly decreasing)
    double lg = (double)log_gamma[s];
    gam = lg > 20.0 ? lg : log1p(exp(lg));
  }
  double th = (double)omega[s] * dte;
  double r  = exp(-gam * dte);
  a_out[s] = make_float2((float)(r * cos(th)), (float)(r * sin(th)));
  double thl = th * (double)LCHUNK;
  double rl  = exp(-gam * dte * (double)LCHUNK);
  A_out[s] = make_float2((float)(rl * cos(thl)), (float)(rl * sin(thl)));
}

// ---------------- gate = sigmoid(x@Wg+bg) * (1 + tanh(sg)*mean|x-z|) ----------------
__global__ __launch_bounds__(256) void gate_kernel(
    const float* __restrict__ x, const float* __restrict__ z,
    const float* __restrict__ Wg, const float* __restrict__ bg,
    const float* __restrict__ sg, float* __restrict__ gate) {
  int m = blockIdx.x * 4 + (threadIdx.x >> 6);
  int lane = threadIdx.x & 63;
  const float* xp = x + (size_t)m * DIMX;
  const float* zp = z + (size_t)m * DIMX;
  float dot = 0.f, sur = 0.f;
  for (int i = lane; i < DIMX; i += 64) {
    float xv = xp[i];
    dot = fmaf(xv, Wg[i], dot);
    sur += fabsf(xv - zp[i]);
  }
#pragma unroll
  for (int o = 32; o > 0; o >>= 1) {
    dot += __shfl_down(dot, o, 64);
    sur += __shfl_down(sur, o, 64);
  }
  if (lane == 0) {
    float gs = 1.f / (1.f + expf(-(dot + bg[0])));
    gate[m] = gs * (1.f + tanhf(sg[0]) * (sur * (1.f / DIMX)));
  }
}

// ---------------- C[m,n] = sum_k X[m,k]*W[n,k] + bias[n] (+C if ACC) ----------------
template<bool ACC>
__global__ __launch_bounds__(256) void gemm_nt(
    const float* __restrict__ X, const float* __restrict__ W,
    const float* __restrict__ bias, float* __restrict__ C,
    int M, int N, int K) {
  __shared__ float Xs[16][64];
  __shared__ float Ws[16][64];
  const int tid = threadIdx.x;
  const int bm = blockIdx.y * 64;
  const int bn = blockIdx.x * 64;
  const int tx = tid & 15;
  const int ty = tid >> 4;
  const int lrow = tid >> 2;
  const int lk = (tid & 3) << 2;
  const float* Xp = X + (size_t)(bm + lrow) * K + lk;
  const float* Wp = W + (size_t)(bn + lrow) * K + lk;
  float acc[4][4] = {};
  for (int kt = 0; kt < K; kt += 16) {
    float4 xa = *(const float4*)(Xp + kt);
    float4 wa = *(const float4*)(Wp + kt);
    __syncthreads();
    Xs[lk + 0][lrow] = xa.x; Xs[lk + 1][lrow] = xa.y;
    Xs[lk + 2][lrow] = xa.z; Xs[lk + 3][lrow] = xa.w;
    Ws[lk + 0][lrow] = wa.x; Ws[lk + 1][lrow] = wa.y;
    Ws[lk + 2][lrow] = wa.z; Ws[lk + 3][lrow] = wa.w;
    __syncthreads();
#pragma unroll
    for (int k = 0; k < 16; ++k) {
      float4 xv = *(const float4*)(&Xs[k][ty << 2]);
      float4 wv = *(const float4*)(&Ws[k][tx << 2]);
      float xr[4] = {xv.x, xv.y, xv.z, xv.w};
      float wr[4] = {wv.x, wv.y, wv.z, wv.w};
#pragma unroll
      for (int i = 0; i < 4; ++i)
#pragma unroll
        for (int j = 0; j < 4; ++j)
          acc[i][j] = fmaf(xr[i], wr[j], acc[i][j]);
    }
  }
#pragma unroll
  for (int i = 0; i < 4; ++i) {
    int m = bm + (ty << 2) + i;
#pragma unroll
    for (int j = 0; j < 4; ++j) {
      int n = bn + (tx << 2) + j;
      float v = acc[i][j] + bias[n];
      if (ACC) v += C[(size_t)m * N + n];
      C[(size_t)m * N + n] = v;
    }
  }
}

// ---------------- U = gate * softplus(blin)*exp(i*pi*tanh(phlin)) * psi ----------------
__global__ __launch_bounds__(256) void u_kernel(
    const float* __restrict__ gate, const float* __restrict__ blin,
    const float* __restrict__ phlin, const float* __restrict__ psi,
    float2* __restrict__ U) {
  int idx = blockIdx.x * 256 + threadIdx.x;
  int m = idx >> 10;
  int s = idx & (SDN - 1);
  float g  = gate[m];
  float bv = softplusf_(blin[idx]);
  float ph = PI_F * tanhf(phlin[idx]);
  float sph, cph;
  sincosf(ph, &sph, &cph);
  float br = bv * cph, bi = bv * sph;
  const float* pp = psi + ((size_t)m << 11);
  float pre = pp[s], pim = pp[SDN + s];
  U[idx] = make_float2(g * (br * pre - bi * pim), g * (br * pim + bi * pre));
}

// ---------------- chunked parallel scan: V[t] = a*V[t-1] + U[t] ----------------
__global__ __launch_bounds__(256) void scan_stage1(
    const float2* __restrict__ U, const float2* __restrict__ a,
    float2* __restrict__ carry) {
  int s = blockIdx.x * 256 + threadIdx.x;
  int c = blockIdx.y, b = blockIdx.z;
  float2 av = a[s];
  float2 V = make_float2(0.f, 0.f);
  const float2* Up = U + (size_t)(b * LSEQ + c * LCHUNK) * SDN + s;
#pragma unroll 4
  for (int t = 0; t < LCHUNK; ++t)
    V = cfma2(av, V, Up[(size_t)t * SDN]);
  carry[(size_t)(b * NCHUNK + c) * SDN + s] = V;
}

__global__ __launch_bounds__(256) void scan_stage2(
    const float2* __restrict__ carry, const float2* __restrict__ A,
    float2* __restrict__ prefix) {
  int s = blockIdx.x * 256 + threadIdx.x;
  int b = blockIdx.z;
  float2 Av = A[s];
  float2 P = make_float2(0.f, 0.f);
  for (int c = 0; c < NCHUNK; ++c) {
    size_t off = (size_t)(b * NCHUNK + c) * SDN + s;
    prefix[off] = P;
    P = cfma2(Av, P, carry[off]);
  }
}

__global__ __launch_bounds__(256) void scan_stage3(
    const float2* __restrict__ U, const float2* __restrict__ a,
    const float2* __restrict__ prefix, float2* __restrict__ Vout) {
  int s = blockIdx.x * 256 + threadIdx.x;
  int c = blockIdx.y, b = blockIdx.z;
  float2 av = a[s];
  float2 V = prefix[(size_t)(b * NCHUNK + c) * SDN + s];
  size_t base = (size_t)(b * LSEQ + c * LCHUNK) * SDN + s;
#pragma unroll 4
  for (int t = 0; t < LCHUNK; ++t) {
    V = cfma2(av, V, U[base + (size_t)t * SDN]);
    Vout[base + (size_t)t * SDN] = V;
  }
}

// ---------------- H_flat: shifted, RMS-normalized scout state ----------------
__global__ __launch_bounds__(256) void hflat_kernel(
    const float2* __restrict__ V, float* __restrict__ Hflat) {
  int m = blockIdx.x;
  int t = m & (LSEQ - 1);
  float2 v[4];
  float sum = 0.f;
#pragma unroll
  for (int i = 0; i < 4; ++i) {
    int s = threadIdx.x + i * 256;
    float2 vv = make_float2(0.f, 0.f);
    if (t > 0) vv = V[(size_t)(m - 1) * SDN + s];
    v[i] = vv;
    sum += vv.x * vv.x + vv.y * vv.y;
  }
  __shared__ float red[256];
  red[threadIdx.x] = sum;
  __syncthreads();
  for (int o = 128; o > 0; o >>= 1) {
    if (threadIdx.x < o) red[threadIdx.x] += red[threadIdx.x + o];
    __syncthreads();
  }
  float inv = 1.0f / sqrtf(red[0] * (1.f / SDN) + 1e-6f);
  float* hr = Hflat + ((size_t)m << 11);
#pragma unroll
  for (int i = 0; i < 4; ++i) {
    int s = threadIdx.x + i * 256;
    hr[s] = v[i].x * inv;
    hr[SDN + s] = v[i].y * inv;
  }
}

// ---------------- simpson + RMS + MIMO + conj(phi) + tau/beta ----------------
__global__ __launch_bounds__(256) void final_kernel(
    const float2* __restrict__ V, const float* __restrict__ phi,
    const float* __restrict__ mimo, const float* __restrict__ tau,
    const float* __restrict__ beta, float* __restrict__ out) {
  int m = blockIdx.x;
  int t = m & (LSEQ - 1);
  __shared__ float2 hl[SDN];
  __shared__ float red[256];
  float sum = 0.f;
#pragma unroll
  for (int i = 0; i < 4; ++i) {
    int s = threadIdx.x + i * 256;
    float2 v0 = V[(size_t)m * SDN + s];
    float2 v1 = make_float2(0.f, 0.f), v2 = make_float2(0.f, 0.f);
    if (t >= 1) v1 = V[(size_t)(m - 1) * SDN + s];
    if (t >= 2) v2 = V[(size_t)(m - 2) * SDN + s];
    float2 h = make_float2((v0.x + 4.f * v1.x + v2.x) * (1.f / 6.f),
                           (v0.y + 4.f * v1.y + v2.y) * (1.f / 6.f));
    hl[s] = h;
    sum += h.x * h.x + h.y * h.y;
  }
  red[threadIdx.x] = sum;
  __syncthreads();
  for (int o = 128; o > 0; o >>= 1) {
    if (threadIdx.x < o) red[threadIdx.x] += red[threadIdx.x + o];
    __syncthreads();
  }
  float inv = 1.0f / sqrtf(red[0] * (1.f / SDN) + 1e-6f);
  float tv = tau[0], bv = beta[0];
  const float* pp = phi + ((size_t)m << 11);
#pragma unroll
  for (int i = 0; i < 4; ++i) {
    int s = threadIdx.x + i * 256;
    int g = s >> 3, q = s & 7;
    const float* wp = mimo + (size_t)g * 64 + q;
    float hr = 0.f, hi = 0.f;
#pragma unroll
    for (int p = 0; p < 8; ++p) {
      float w = wp[p * 8];
      float2 hp = hl[(g << 3) + p];
      hr = fmaf(hp.x, w, hr);
      hi = fmaf(hp.y, w, hi);
    }
    hr *= inv; hi *= inv;
    float o1 = hr * pp[s] + hi * pp[SDN + s];
    out[(size_t)m * SDN + s] = tv * o1 + bv;
  }
}

extern "C" void kernel_launch(void* const* d_in, const int* in_sizes, int n_in,
                              void* d_out, int out_size, void* d_ws, size_t ws_size,
                              hipStream_t stream) {
  const float* x      = (const float*)d_in[0];
  const float* z_prev = (const float*)d_in[1];
  const float* W_psi  = (const float*)d_in[2];
  const float* b_psi  = (const float*)d_in[3];
  const float* W_phi  = (const float*)d_in[4];
  const float* b_phi  = (const float*)d_in[5];
  const float* W_gate = (const float*)d_in[6];
  const float* b_gate = (const float*)d_in[7];
  const float* s_gain = (const float*)d_in[8];
  const float* omega  = (const float*)d_in[9];
  const float* log_g  = (const float*)d_in[10];
  const float* dt     = (const float*)d_in[11];
  const float* W_bs   = (const float*)d_in[12];
  const float* b_bs   = (const float*)d_in[13];
  const float* W_ps   = (const float*)d_in[14];
  const float* b_ps   = (const float*)d_in[15];
  const float* W_btx  = (const float*)d_in[16];
  const float* b_btx  = (const float*)d_in[17];
  const float* W_bth  = (const float*)d_in[18];
  const float* b_bth  = (const float*)d_in[19];
  const float* W_ptx  = (const float*)d_in[20];
  const float* b_ptx  = (const float*)d_in[21];
  const float* mimo_w = (const float*)d_in[22];
  const float* tau    = (const float*)d_in[23];
  const float* beta   = (const float*)d_in[24];
  float* out = (float*)d_out;

  float* ws = (float*)d_ws;
  const size_t M1 = 1 << 20;
  float*  psiB  = ws;                       // 8M floats (psi_raw, BLx2SD)
  float*  bsB   = ws + 8 * M1;              // 4M
  float*  psB   = ws + 12 * M1;             // 4M
  float*  hflat = ws + 8 * M1;              // 8M (aliases bsB+psB, used after they die)
  float*  btxB  = ws + 16 * M1;             // 4M (b_true linear accumulator)
  float*  ptxB  = ws + 20 * M1;             // 4M
  float2* U     = (float2*)(ws + 24 * M1);  // 8M floats
  float*  phiB  = ws + 24 * M1;             // aliases U (phi computed after scan2)
  float2* V     = (float2*)(ws + 32 * M1);  // 8M floats
  float*  gate  = ws + 40 * M1;                          // 4096
  float2* ac    = (float2*)(ws + 40 * M1 + 4096);        // 1024 float2
  float2* Ac    = (float2*)(ws + 40 * M1 + 4096 + 2048); // 1024 float2
  float2* carry  = (float2*)(ws + 40 * M1 + 8192);           // 32768 float2
  float2* prefix = (float2*)(ws + 40 * M1 + 8192 + 65536);   // 32768 float2
  (void)ws_size; (void)in_sizes; (void)n_in; (void)out_size;

  dim3 blk(256);

  // coefficients + gate
  coef_kernel<<<dim3(4), blk, 0, stream>>>(omega, log_g, dt, ac, Ac);
  gate_kernel<<<dim3(BLROWS / 4), blk, 0, stream>>>(x, z_prev, W_gate, b_gate, s_gain, gate);

  // projections of x
  gemm_nt<false><<<dim3(2 * SDN / 64, BLROWS / 64), blk, 0, stream>>>(x, W_psi, b_psi, psiB, BLROWS, 2 * SDN, DIMX);
  gemm_nt<false><<<dim3(SDN / 64, BLROWS / 64), blk, 0, stream>>>(x, W_bs,  b_bs,  bsB,  BLROWS, SDN, DIMX);
  gemm_nt<false><<<dim3(SDN / 64, BLROWS / 64), blk, 0, stream>>>(x, W_ps,  b_ps,  psB,  BLROWS, SDN, DIMX);
  gemm_nt<false><<<dim3(SDN / 64, BLROWS / 64), blk, 0, stream>>>(x, W_btx, b_btx, btxB, BLROWS, SDN, DIMX);
  gemm_nt<false><<<dim3(SDN / 64, BLROWS / 64), blk, 0, stream>>>(x, W_ptx, b_ptx, ptxB, BLROWS, SDN, DIMX);

  // U_scout, scan 1 (kernel_raw conv == first-order recurrence)
  u_kernel<<<dim3(BLROWS * SDN / 256), blk, 0, stream>>>(gate, bsB, psB, psiB, U);
  scan_stage1<<<dim3(SDN / 256, NCHUNK, BATCHN), blk, 0, stream>>>(U, ac, carry);
  scan_stage2<<<dim3(SDN / 256, 1, BATCHN), blk, 0, stream>>>(carry, Ac, prefix);
  scan_stage3<<<dim3(SDN / 256, NCHUNK, BATCHN), blk, 0, stream>>>(U, ac, prefix, V);

  // H_flat (shift + rms normalize), then b_true = softplus(x@Wbtx+b + Hflat@Wbth+b)
  hflat_kernel<<<dim3(BLROWS), blk, 0, stream>>>(V, hflat);
  gemm_nt<true><<<dim3(SDN / 64, BLROWS / 64), blk, 0, stream>>>(hflat, W_bth, b_bth, btxB, BLROWS, SDN, 2 * SDN);

  // U_true, scan 2
  u_kernel<<<dim3(BLROWS * SDN / 256), blk, 0, stream>>>(gate, btxB, ptxB, psiB, U);
  scan_stage1<<<dim3(SDN / 256, NCHUNK, BATCHN), blk, 0, stream>>>(U, ac, carry);
  scan_stage2<<<dim3(SDN / 256, 1, BATCHN), blk, 0, stream>>>(carry, Ac, prefix);
  scan_stage3<<<dim3(SDN / 256, NCHUNK, BATCHN), blk, 0, stream>>>(U, ac, prefix, V);

  // phi projection (into dead U slot), then fused simpson+rms+mimo+phi epilogue
  gemm_nt<false><<<dim3(2 * SDN / 64, BLROWS / 64), blk, 0, stream>>>(x, W_phi, b_phi, phiB, BLROWS, 2 * SDN, DIMX);
  final_kernel<<<dim3(BLROWS), blk, 0, stream>>>(V, phiB, mimo_w, tau, beta, out);
}

// Round 2
// 377.459 us; speedup vs baseline: 3.6234x; 3.6234x over previous
//
#include <hip/hip_runtime.h>
#include <math.h>

#define DIMX   1024
#define SDN    1024
#define BATCHN 2
#define LSEQ   2048
#define BLROWS (BATCHN*LSEQ)
#define NCHUNK 32
#define LCHUNK (LSEQ/NCHUNK)
#define PI_F   3.14159265358979f

typedef unsigned short ushort_t;
typedef __bf16 bf16_t;
typedef bf16_t bf16x8 __attribute__((ext_vector_type(8)));
typedef float f32x4 __attribute__((ext_vector_type(4)));

__device__ __forceinline__ float softplusf_(float x) {
  return x > 20.0f ? x : log1pf(expf(x));
}

__device__ __forceinline__ ushort_t f2bf_rne(float f) {
  unsigned u = __float_as_uint(f);
  u = u + 0x7fffu + ((u >> 16) & 1u);
  return (ushort_t)(u >> 16);
}

__device__ __forceinline__ float2 cfma2(float2 a, float2 v, float2 u) {
  float re = fmaf(a.x, v.x, fmaf(-a.y, v.y, u.x));
  float im = fmaf(a.x, v.y, fmaf(a.y, v.x, u.y));
  return make_float2(re, im);
}

__device__ __forceinline__ void gload_lds16(const ushort_t* g, ushort_t* l) {
  __builtin_amdgcn_global_load_lds(
      (const __attribute__((address_space(1))) void*)g,
      (__attribute__((address_space(3))) void*)l, 16, 0, 0);
}

// ---------------- fp32 -> bf16 (RNE), vector4 ----------------
__global__ __launch_bounds__(256) void f2bf_kernel(
    const float* __restrict__ in, ushort_t* __restrict__ out) {
  int i = (blockIdx.x * 256 + threadIdx.x) * 4;
  float4 v = *(const float4*)(in + i);
  ushort4 o;
  o.x = f2bf_rne(v.x); o.y = f2bf_rne(v.y);
  o.z = f2bf_rne(v.z); o.w = f2bf_rne(v.w);
  *(ushort4*)(out + i) = o;
}

// ---------------- coefficients: a = exp(lam*dt), A = a^LCHUNK ----------------
__global__ void coef_kernel(const float* __restrict__ omega,
                            const float* __restrict__ log_gamma,
                            const float* __restrict__ dt,
                            float2* __restrict__ a_out,
                            float2* __restrict__ A_out) {
  int s = blockIdx.x * blockDim.x + threadIdx.x;
  if (s >= SDN) return;
  double dtv = (double)dt[0];
  double dte = dtv > 20.0 ? dtv : log1p(exp(dtv));
  double gam = 0.0;
  if (s < SDN - SDN / 4) {  // band0 = indices [768,1023] (freqs strictly decreasing)
    double lg = (double)log_gamma[s];
    gam = lg > 20.0 ? lg : log1p(exp(lg));
  }
  double th = (double)omega[s] * dte;
  double r  = exp(-gam * dte);
  a_out[s] = make_float2((float)(r * cos(th)), (float)(r * sin(th)));
  double thl = th * (double)LCHUNK;
  double rl  = exp(-gam * dte * (double)LCHUNK);
  A_out[s] = make_float2((float)(rl * cos(thl)), (float)(rl * sin(thl)));
}

// ---------------- gate ----------------
__global__ __launch_bounds__(256) void gate_kernel(
    const float* __restrict__ x, const float* __restrict__ z,
    const float* __restrict__ Wg, const float* __restrict__ bg,
    const float* __restrict__ sg, float* __restrict__ gate) {
  int m = blockIdx.x * 4 + (threadIdx.x >> 6);
  int lane = threadIdx.x & 63;
  const float* xp = x + (size_t)m * DIMX;
  const float* zp = z + (size_t)m * DIMX;
  float dot = 0.f, sur = 0.f;
  for (int i = lane; i < DIMX; i += 64) {
    float xv = xp[i];
    dot = fmaf(xv, Wg[i], dot);
    sur += fabsf(xv - zp[i]);
  }
#pragma unroll
  for (int o = 32; o > 0; o >>= 1) {
    dot += __shfl_down(dot, o, 64);
    sur += __shfl_down(sur, o, 64);
  }
  if (lane == 0) {
    float gs = 1.f / (1.f + expf(-(dot + bg[0])));
    gate[m] = gs * (1.f + tanhf(sg[0]) * (sur * (1.f / DIMX)));
  }
}

// ---------------- bf16 MFMA GEMM: C[m,n] = sum_k X[m,k]*W[n,k] + bias[n] (+C) ----------------
// 128x128 tile, BK=32, 4 waves (2x2), 16x16x32 MFMA, global_load_lds(16B), LDS dbuf.
template<bool ACC>
__global__ __launch_bounds__(256, 2) void gemm_bf16(
    const ushort_t* __restrict__ Xb, const ushort_t* __restrict__ Wb,
    const float* __restrict__ bias, float* __restrict__ C,
    int N, int K) {
  __shared__ ushort_t As[2][4096];  // [buf][128 rows][32 k] row-major
  __shared__ ushort_t Bs[2][4096];
  const int tid = threadIdx.x;
  const int w = tid >> 6, l = tid & 63;
  const int bm = blockIdx.y * 128, bn = blockIdx.x * 128;
  const int wr = w >> 1, wc = w & 1;

  // staging: element-of-512 e = p*256+tid covers 8 bf16; row=e>>2, k0=(e&3)*8
  const ushort_t* ga0 = Xb + (size_t)(bm + (tid >> 2)) * K + (tid & 3) * 8;
  const ushort_t* ga1 = Xb + (size_t)(bm + 64 + (tid >> 2)) * K + (tid & 3) * 8;
  const ushort_t* gb0 = Wb + (size_t)(bn + (tid >> 2)) * K + (tid & 3) * 8;
  const ushort_t* gb1 = Wb + (size_t)(bn + 64 + (tid >> 2)) * K + (tid & 3) * 8;

  f32x4 acc[4][4] = {};
  const int nk = K >> 5;

#define STAGE(buf, kt)                                   \
  do {                                                   \
    gload_lds16(ga0 + (kt), &As[buf][w * 512]);          \
    gload_lds16(ga1 + (kt), &As[buf][2048 + w * 512]);   \
    gload_lds16(gb0 + (kt), &Bs[buf][w * 512]);          \
    gload_lds16(gb1 + (kt), &Bs[buf][2048 + w * 512]);   \
  } while (0)

  STAGE(0, 0);
  __syncthreads();

  const int rl = l & 15, kh = l >> 4;
  for (int kt = 0; kt < nk; ++kt) {
    int cur = kt & 1;
    if (kt + 1 < nk) STAGE(cur ^ 1, (kt + 1) * 32);
    const uint4* Af = (const uint4*)As[cur];
    const uint4* Bf = (const uint4*)Bs[cur];
    bf16x8 a[4], b[4];
#pragma unroll
    for (int i = 0; i < 4; ++i)
      a[i] = __builtin_bit_cast(bf16x8, Af[(wr * 64 + i * 16 + rl) * 4 + kh]);
#pragma unroll
    for (int j = 0; j < 4; ++j)
      b[j] = __builtin_bit_cast(bf16x8, Bf[(wc * 64 + j * 16 + rl) * 4 + kh]);
#pragma unroll
    for (int i = 0; i < 4; ++i)
#pragma unroll
      for (int j = 0; j < 4; ++j)
        acc[i][j] = __builtin_amdgcn_mfma_f32_16x16x32_bf16(a[i], b[j], acc[i][j], 0, 0, 0);
    __syncthreads();
  }
#undef STAGE

#pragma unroll
  for (int i = 0; i < 4; ++i) {
    int mrow = bm + wr * 64 + i * 16 + (l >> 4) * 4;
#pragma unroll
    for (int j = 0; j < 4; ++j) {
      int ncol = bn + wc * 64 + j * 16 + (l & 15);
      float bv = bias[ncol];
#pragma unroll
      for (int r = 0; r < 4; ++r) {
        size_t off = (size_t)(mrow + r) * N + ncol;
        float v = acc[i][j][r] + bv;
        if (ACC) v += C[off];
        C[off] = v;
      }
    }
  }
}

// ---------------- U = gate * softplus(blin)*exp(i*pi*tanh(phlin)) * psi ----------------
__global__ __launch_bounds__(256) void u_kernel(
    const float* __restrict__ gate, const float* __restrict__ blin,
    const float* __restrict__ phlin, const float* __restrict__ psi,
    float2* __restrict__ U) {
  int idx = blockIdx.x * 256 + threadIdx.x;
  int m = idx >> 10;
  int s = idx & (SDN - 1);
  float g  = gate[m];
  float bv = softplusf_(blin[idx]);
  float ph = PI_F * tanhf(phlin[idx]);
  float sph, cph;
  sincosf(ph, &sph, &cph);
  float br = bv * cph, bi = bv * sph;
  const float* pp = psi + ((size_t)m << 11);
  float pre = pp[s], pim = pp[SDN + s];
  U[idx] = make_float2(g * (br * pre - bi * pim), g * (br * pim + bi * pre));
}

// ---------------- chunked parallel scan ----------------
__global__ __launch_bounds__(256) void scan_stage1(
    const float2* __restrict__ U, const float2* __restrict__ a,
    float2* __restrict__ carry) {
  int s = blockIdx.x * 256 + threadIdx.x;
  int c = blockIdx.y, b = blockIdx.z;
  float2 av = a[s];
  float2 V = make_float2(0.f, 0.f);
  const float2* Up = U + (size_t)(b * LSEQ + c * LCHUNK) * SDN + s;
#pragma unroll 4
  for (int t = 0; t < LCHUNK; ++t)
    V = cfma2(av, V, Up[(size_t)t * SDN]);
  carry[(size_t)(b * NCHUNK + c) * SDN + s] = V;
}

__global__ __launch_bounds__(256) void scan_stage2(
    const float2* __restrict__ carry, const float2* __restrict__ A,
    float2* __restrict__ prefix) {
  int s = blockIdx.x * 256 + threadIdx.x;
  int b = blockIdx.z;
  float2 Av = A[s];
  float2 P = make_float2(0.f, 0.f);
  for (int c = 0; c < NCHUNK; ++c) {
    size_t off = (size_t)(b * NCHUNK + c) * SDN + s;
    prefix[off] = P;
    P = cfma2(Av, P, carry[off]);
  }
}

// in-place: Vout may alias U (read-then-write per element, sequential per thread)
__global__ __launch_bounds__(256) void scan_stage3(
    const float2* __restrict__ U, const float2* __restrict__ a,
    const float2* __restrict__ prefix, float2* __restrict__ Vout) {
  int s = blockIdx.x * 256 + threadIdx.x;
  int c = blockIdx.y, b = blockIdx.z;
  float2 av = a[s];
  float2 V = prefix[(size_t)(b * NCHUNK + c) * SDN + s];
  size_t base = (size_t)(b * LSEQ + c * LCHUNK) * SDN + s;
#pragma unroll 4
  for (int t = 0; t < LCHUNK; ++t) {
    V = cfma2(av, V, U[base + (size_t)t * SDN]);
    Vout[base + (size_t)t * SDN] = V;
  }
}

// ---------------- H_flat (bf16): shifted, RMS-normalized scout state ----------------
__global__ __launch_bounds__(256) void hflat_kernel(
    const float2* __restrict__ V, ushort_t* __restrict__ Hflat) {
  int m = blockIdx.x;
  int t = m & (LSEQ - 1);
  float2 v[4];
  float sum = 0.f;
#pragma unroll
  for (int i = 0; i < 4; ++i) {
    int s = threadIdx.x + i * 256;
    float2 vv = make_float2(0.f, 0.f);
    if (t > 0) vv = V[(size_t)(m - 1) * SDN + s];
    v[i] = vv;
    sum += vv.x * vv.x + vv.y * vv.y;
  }
  __shared__ float red[256];
  red[threadIdx.x] = sum;
  __syncthreads();
  for (int o = 128; o > 0; o >>= 1) {
    if (threadIdx.x < o) red[threadIdx.x] += red[threadIdx.x + o];
    __syncthreads();
  }
  float inv = 1.0f / sqrtf(red[0] * (1.f / SDN) + 1e-6f);
  ushort_t* hr = Hflat + ((size_t)m << 11);
#pragma unroll
  for (int i = 0; i < 4; ++i) {
    int s = threadIdx.x + i * 256;
    hr[s] = f2bf_rne(v[i].x * inv);
    hr[SDN + s] = f2bf_rne(v[i].y * inv);
  }
}

// ---------------- simpson + RMS + MIMO + conj(phi) + tau/beta ----------------
__global__ __launch_bounds__(256) void final_kernel(
    const float2* __restrict__ V, const float* __restrict__ phi,
    const float* __restrict__ mimo, const float* __restrict__ tau,
    const float* __restrict__ beta, float* __restrict__ out) {
  int m = blockIdx.x;
  int t = m & (LSEQ - 1);
  __shared__ float2 hl[SDN];
  __shared__ float red[256];
  float sum = 0.f;
#pragma unroll
  for (int i = 0; i < 4; ++i) {
    int s = threadIdx.x + i * 256;
    float2 v0 = V[(size_t)m * SDN + s];
    float2 v1 = make_float2(0.f, 0.f), v2 = make_float2(0.f, 0.f);
    if (t >= 1) v1 = V[(size_t)(m - 1) * SDN + s];
    if (t >= 2) v2 = V[(size_t)(m - 2) * SDN + s];
    float2 h = make_float2((v0.x + 4.f * v1.x + v2.x) * (1.f / 6.f),
                           (v0.y + 4.f * v1.y + v2.y) * (1.f / 6.f));
    hl[s] = h;
    sum += h.x * h.x + h.y * h.y;
  }
  red[threadIdx.x] = sum;
  __syncthreads();
  for (int o = 128; o > 0; o >>= 1) {
    if (threadIdx.x < o) red[threadIdx.x] += red[threadIdx.x + o];
    __syncthreads();
  }
  float inv = 1.0f / sqrtf(red[0] * (1.f / SDN) + 1e-6f);
  float tv = tau[0], bv = beta[0];
  const float* pp = phi + ((size_t)m << 11);
#pragma unroll
  for (int i = 0; i < 4; ++i) {
    int s = threadIdx.x + i * 256;
    int g = s >> 3, q = s & 7;
    const float* wp = mimo + (size_t)g * 64 + q;
    float hr = 0.f, hi = 0.f;
#pragma unroll
    for (int p = 0; p < 8; ++p) {
      float wv = wp[p * 8];
      float2 hp = hl[(g << 3) + p];
      hr = fmaf(hp.x, wv, hr);
      hi = fmaf(hp.y, wv, hi);
    }
    hr *= inv; hi *= inv;
    float o1 = hr * pp[s] + hi * pp[SDN + s];
    out[(size_t)m * SDN + s] = tv * o1 + bv;
  }
}

extern "C" void kernel_launch(void* const* d_in, const int* in_sizes, int n_in,
                              void* d_out, int out_size, void* d_ws, size_t ws_size,
                              hipStream_t stream) {
  const float* x      = (const float*)d_in[0];
  const float* z_prev = (const float*)d_in[1];
  const float* W_psi  = (const float*)d_in[2];
  const float* b_psi  = (const float*)d_in[3];
  const float* W_phi  = (const float*)d_in[4];
  const float* b_phi  = (const float*)d_in[5];
  const float* W_gate = (const float*)d_in[6];
  const float* b_gate = (const float*)d_in[7];
  const float* s_gain = (const float*)d_in[8];
  const float* omega  = (const float*)d_in[9];
  const float* log_g  = (const float*)d_in[10];
  const float* dt     = (const float*)d_in[11];
  const float* W_bs   = (const float*)d_in[12];
  const float* b_bs   = (const float*)d_in[13];
  const float* W_ps   = (const float*)d_in[14];
  const float* b_ps   = (const float*)d_in[15];
  const float* W_btx  = (const float*)d_in[16];
  const float* b_btx  = (const float*)d_in[17];
  const float* W_bth  = (const float*)d_in[18];
  const float* b_bth  = (const float*)d_in[19];
  const float* W_ptx  = (const float*)d_in[20];
  const float* b_ptx  = (const float*)d_in[21];
  const float* mimo_w = (const float*)d_in[22];
  const float* tau    = (const float*)d_in[23];
  const float* beta   = (const float*)d_in[24];
  float* out = (float*)d_out;

  float* ws = (float*)d_ws;
  const size_t M1 = 1 << 20;
  float*    psiB   = ws;                          // 8M floats; later phiB
  float*    phiB   = ws;                          // alias (psi dead after u_kernel#2)
  float*    bsB    = ws + 8 * M1;                 // 4M floats
  ushort_t* hflatB = (ushort_t*)(ws + 8 * M1);    // 8M bf16 (alias, after bsB dies)
  float*    psB    = ws + 12 * M1;                // 4M floats
  ushort_t* wbthb  = (ushort_t*)(ws + 12 * M1);   // 2M bf16 (alias, after psB dies)
  float*    btxB   = ws + 16 * M1;                // 4M floats
  float*    ptxB   = ws + 20 * M1;                // 4M floats
  float2*   U      = (float2*)(ws + 24 * M1);     // 4M float2; scan3 in-place -> V
  float2*   V      = U;
  ushort_t* xb     = (ushort_t*)(ws + 32 * M1);   // 4M bf16
  ushort_t* wpsib  = (ushort_t*)(ws + 34 * M1);   // 2M bf16
  ushort_t* wphib  = (ushort_t*)(ws + 35 * M1);   // 2M bf16
  ushort_t* wbsb   = (ushort_t*)(ws + 36 * M1);   // 1M bf16
  ushort_t* wpsb   = (ushort_t*)(ws + 36 * M1 + 512 * 1024);
  ushort_t* wbtxb  = (ushort_t*)(ws + 37 * M1);
  ushort_t* wptxb  = (ushort_t*)(ws + 37 * M1 + 512 * 1024);
  float*    gate   = ws + 38 * M1;                            // 4096 floats
  float2*   ac     = (float2*)(ws + 38 * M1 + 4096);          // 1024 float2
  float2*   Ac     = (float2*)(ws + 38 * M1 + 8192);          // 1024 float2
  float2*   carry  = (float2*)(ws + 38 * M1 + 16384);         // 64K float2
  float2*   prefix = (float2*)(ws + 38 * M1 + 16384 + 131072);// 64K float2
  (void)ws_size; (void)in_sizes; (void)n_in; (void)out_size;

  dim3 blk(256);

  // coefficients + gate + conversions
  coef_kernel<<<dim3(4), blk, 0, stream>>>(omega, log_g, dt, ac, Ac);
  gate_kernel<<<dim3(BLROWS / 4), blk, 0, stream>>>(x, z_prev, W_gate, b_gate, s_gain, gate);
  f2bf_kernel<<<dim3(4096), blk, 0, stream>>>(x, xb);
  f2bf_kernel<<<dim3(2048), blk, 0, stream>>>(W_psi, wpsib);
  f2bf_kernel<<<dim3(2048), blk, 0, stream>>>(W_phi, wphib);
  f2bf_kernel<<<dim3(1024), blk, 0, stream>>>(W_bs, wbsb);
  f2bf_kernel<<<dim3(1024), blk, 0, stream>>>(W_ps, wpsb);
  f2bf_kernel<<<dim3(1024), blk, 0, stream>>>(W_btx, wbtxb);
  f2bf_kernel<<<dim3(1024), blk, 0, stream>>>(W_ptx, wptxb);

  // projections of x (bf16 MFMA)
  gemm_bf16<false><<<dim3(16, 32), blk, 0, stream>>>(xb, wpsib, b_psi, psiB, 2 * SDN, DIMX);
  gemm_bf16<false><<<dim3(8, 32), blk, 0, stream>>>(xb, wbsb,  b_bs,  bsB,  SDN, DIMX);
  gemm_bf16<false><<<dim3(8, 32), blk, 0, stream>>>(xb, wpsb,  b_ps,  psB,  SDN, DIMX);
  gemm_bf16<false><<<dim3(8, 32), blk, 0, stream>>>(xb, wbtxb, b_btx, btxB, SDN, DIMX);
  gemm_bf16<false><<<dim3(8, 32), blk, 0, stream>>>(xb, wptxb, b_ptx, ptxB, SDN, DIMX);

  // U_scout, scan 1
  u_kernel<<<dim3(BLROWS * SDN / 256), blk, 0, stream>>>(gate, bsB, psB, psiB, U);
  f2bf_kernel<<<dim3(2048), blk, 0, stream>>>(W_bth, wbthb);  // psB now dead
  scan_stage1<<<dim3(SDN / 256, NCHUNK, BATCHN), blk, 0, stream>>>(U, ac, carry);
  scan_stage2<<<dim3(SDN / 256, 1, BATCHN), blk, 0, stream>>>(carry, Ac, prefix);
  scan_stage3<<<dim3(SDN / 256, NCHUNK, BATCHN), blk, 0, stream>>>(U, ac, prefix, V);

  // H_flat (bf16), b_true accumulate GEMM
  hflat_kernel<<<dim3(BLROWS), blk, 0, stream>>>(V, hflatB);
  gemm_bf16<true><<<dim3(8, 32), blk, 0, stream>>>(hflatB, wbthb, b_bth, btxB, SDN, 2 * SDN);

  // U_true, scan 2
  u_kernel<<<dim3(BLROWS * SDN / 256), blk, 0, stream>>>(gate, btxB, ptxB, psiB, U);
  scan_stage1<<<dim3(SDN / 256, NCHUNK, BATCHN), blk, 0, stream>>>(U, ac, carry);
  scan_stage2<<<dim3(SDN / 256, 1, BATCHN), blk, 0, stream>>>(carry, Ac, prefix);
  scan_stage3<<<dim3(SDN / 256, NCHUNK, BATCHN), blk, 0, stream>>>(U, ac, prefix, V);

  // phi projection (into dead psi slot), fused epilogue
  gemm_bf16<false><<<dim3(16, 32), blk, 0, stream>>>(xb, wphib, b_phi, phiB, 2 * SDN, DIMX);
  final_kernel<<<dim3(BLROWS), blk, 0, stream>>>(V, phiB, mimo_w, tau, beta, out);
}

// Round 4
// 263.034 us; speedup vs baseline: 5.1997x; 1.4350x over previous
//
#include <hip/hip_runtime.h>
#include <math.h>

#define DIMX   1024
#define SDN    1024
#define BATCHN 2
#define LSEQ   2048
#define BLROWS (BATCHN*LSEQ)
#define NCHUNK 32
#define LCHUNK (LSEQ/NCHUNK)
#define PI_F   3.14159265358979f

typedef unsigned short ushort_t;
typedef __bf16 bf16_t;
typedef bf16_t bf16x8 __attribute__((ext_vector_type(8)));
typedef float f32x4 __attribute__((ext_vector_type(4)));

__device__ __forceinline__ float softplusf_(float x) {
  return x > 20.0f ? x : log1pf(expf(x));
}

__device__ __forceinline__ ushort_t f2bf_rne(float f) {
  unsigned u = __float_as_uint(f);
  u = u + 0x7fffu + ((u >> 16) & 1u);
  return (ushort_t)(u >> 16);
}

__device__ __forceinline__ float bf2f(ushort_t u) {
  return __uint_as_float(((unsigned)u) << 16);
}

__device__ __forceinline__ float2 cfma2(float2 a, float2 v, float2 u) {
  float re = fmaf(a.x, v.x, fmaf(-a.y, v.y, u.x));
  float im = fmaf(a.x, v.y, fmaf(a.y, v.x, u.y));
  return make_float2(re, im);
}

__device__ __forceinline__ void gload_lds16(const ushort_t* g, ushort_t* l) {
  __builtin_amdgcn_global_load_lds(
      (const __attribute__((address_space(1))) void*)g,
      (__attribute__((address_space(3))) void*)l, 16, 0, 0);
}

// ---------------- fp32 -> bf16 (RNE), vector4 ----------------
__global__ __launch_bounds__(256) void f2bf_kernel(
    const float* __restrict__ in, ushort_t* __restrict__ out) {
  int i = (blockIdx.x * 256 + threadIdx.x) * 4;
  float4 v = *(const float4*)(in + i);
  ushort4 o;
  o.x = f2bf_rne(v.x); o.y = f2bf_rne(v.y);
  o.z = f2bf_rne(v.z); o.w = f2bf_rne(v.w);
  *(ushort4*)(out + i) = o;
}

// ---------------- concat biases into one [8192] vector ----------------
__global__ __launch_bounds__(256) void bcat_kernel(
    const float* __restrict__ b_psi, const float* __restrict__ b_phi,
    const float* __restrict__ b_bs, const float* __restrict__ b_ps,
    const float* __restrict__ b_btx, const float* __restrict__ b_ptx,
    float* __restrict__ bcat) {
  int n = blockIdx.x * 256 + threadIdx.x;
  float v;
  if (n < 2048) v = b_psi[n];
  else if (n < 4096) v = b_phi[n - 2048];
  else if (n < 5120) v = b_bs[n - 4096];
  else if (n < 6144) v = b_ps[n - 5120];
  else if (n < 7168) v = b_btx[n - 6144];
  else v = b_ptx[n - 7168];
  bcat[n] = v;
}

// ---------------- coefficients: a = exp(lam*dt), A = a^LCHUNK ----------------
__global__ void coef_kernel(const float* __restrict__ omega,
                            const float* __restrict__ log_gamma,
                            const float* __restrict__ dt,
                            float2* __restrict__ a_out,
                            float2* __restrict__ A_out) {
  int s = blockIdx.x * blockDim.x + threadIdx.x;
  if (s >= SDN) return;
  double dtv = (double)dt[0];
  double dte = dtv > 20.0 ? dtv : log1p(exp(dtv));
  double gam = 0.0;
  if (s < SDN - SDN / 4) {  // band0 = indices [768,1023] (freqs strictly decreasing)
    double lg = (double)log_gamma[s];
    gam = lg > 20.0 ? lg : log1p(exp(lg));
  }
  double th = (double)omega[s] * dte;
  double r  = exp(-gam * dte);
  a_out[s] = make_float2((float)(r * cos(th)), (float)(r * sin(th)));
  double thl = th * (double)LCHUNK;
  double rl  = exp(-gam * dte * (double)LCHUNK);
  A_out[s] = make_float2((float)(rl * cos(thl)), (float)(rl * sin(thl)));
}

// ---------------- gate ----------------
__global__ __launch_bounds__(256) void gate_kernel(
    const float* __restrict__ x, const float* __restrict__ z,
    const float* __restrict__ Wg, const float* __restrict__ bg,
    const float* __restrict__ sg, float* __restrict__ gate) {
  int m = blockIdx.x * 4 + (threadIdx.x >> 6);
  int lane = threadIdx.x & 63;
  const float* xp = x + (size_t)m * DIMX;
  const float* zp = z + (size_t)m * DIMX;
  float dot = 0.f, sur = 0.f;
  for (int i = lane; i < DIMX; i += 64) {
    float xv = xp[i];
    dot = fmaf(xv, Wg[i], dot);
    sur += fabsf(xv - zp[i]);
  }
#pragma unroll
  for (int o = 32; o > 0; o >>= 1) {
    dot += __shfl_down(dot, o, 64);
    sur += __shfl_down(sur, o, 64);
  }
  if (lane == 0) {
    float gs = 1.f / (1.f + expf(-(dot + bg[0])));
    gate[m] = gs * (1.f + tanhf(sg[0]) * (sur * (1.f / DIMX)));
  }
}

// ---------------- bf16 MFMA GEMM ----------------
// 128x128 tile, BK=32, 4 waves (2x2), 16x16x32 MFMA, global_load_lds(16B),
// LDS dbuf, chunk-rotation LDS swizzle (pre-swizzled global source).
// MODE 0: fused x-projection GEMM. grid=2048 1-D, XCD-rect swizzled tiles.
//         K=1024, N=8192, out bf16 proj[4096][8192] (+bias).
// MODE 1: split-K bth GEMM. grid (8,32,2). X=hflat ld2048, W ld2048,
//         k-slice z: [z*1024, z*1024+1024). out bf16 partial at Cb + z*4M (no bias).
template<int MODE>
__global__ __launch_bounds__(256, 2) void gemm_bf16(
    const ushort_t* __restrict__ Xb, const ushort_t* __restrict__ Wb,
    const float* __restrict__ bias, ushort_t* __restrict__ Cb) {
  __shared__ ushort_t As[2][4096];  // [buf][128 rows][32 k] (granule-rotated)
  __shared__ ushort_t Bs[2][4096];
  const int tid = threadIdx.x;
  const int w = tid >> 6, l = tid & 63;
  int bm, bn, ldx, ldw;
  const ushort_t *Xp, *Wp;
  if (MODE == 0) {
    int b = blockIdx.x;
    int xcd = b & 7, idx = b >> 3;
    int tx = ((xcd & 3) << 4) + (idx & 15);   // 0..63
    int ty = ((xcd >> 2) << 4) + (idx >> 4);  // 0..31
    bm = ty << 7; bn = tx << 7;
    ldx = 1024; ldw = 1024;
    Xp = Xb; Wp = Wb;
  } else {
    bm = blockIdx.y << 7; bn = blockIdx.x << 7;
    ldx = 2048; ldw = 2048;
    Xp = Xb + blockIdx.z * 1024;
    Wp = Wb + blockIdx.z * 1024;
  }
  const int wr = w >> 1, wc = w & 1;

  // staging: lane tid stages LDS granule tid (row=tid>>2, chunk'=tid&3);
  // content chunk c = (chunk' - (row>>1)) & 3  (granule rotation)
  const int srow = tid >> 2;
  const int c8 = (((tid & 3) - (tid >> 3)) & 3) << 3;
  const ushort_t* ga0 = Xp + (size_t)(bm + srow) * ldx + c8;
  const ushort_t* ga1 = Xp + (size_t)(bm + 64 + srow) * ldx + c8;
  const ushort_t* gb0 = Wp + (size_t)(bn + srow) * ldw + c8;
  const ushort_t* gb1 = Wp + (size_t)(bn + 64 + srow) * ldw + c8;

  f32x4 acc[4][4] = {};
  const int nk = 32;  // K-slice is always 1024

#define STAGE(buf, kt)                                   \
  do {                                                   \
    gload_lds16(ga0 + (kt), &As[buf][w * 512]);          \
    gload_lds16(ga1 + (kt), &As[buf][2048 + w * 512]);   \
    gload_lds16(gb0 + (kt), &Bs[buf][w * 512]);          \
    gload_lds16(gb1 + (kt), &Bs[buf][2048 + w * 512]);   \
  } while (0)

  STAGE(0, 0);
  __syncthreads();

  const int rl = l & 15, kh = l >> 4;
  const int chunkp = (kh + (rl >> 1)) & 3;  // rotated granule holding chunk kh
  for (int kt = 0; kt < nk; ++kt) {
    int cur = kt & 1;
    if (kt + 1 < nk) STAGE(cur ^ 1, (kt + 1) * 32);
    const uint4* Af = (const uint4*)As[cur];
    const uint4* Bf = (const uint4*)Bs[cur];
    bf16x8 a[4], b[4];
#pragma unroll
    for (int i = 0; i < 4; ++i)
      a[i] = __builtin_bit_cast(bf16x8, Af[(wr * 64 + i * 16 + rl) * 4 + chunkp]);
#pragma unroll
    for (int j = 0; j < 4; ++j)
      b[j] = __builtin_bit_cast(bf16x8, Bf[(wc * 64 + j * 16 + rl) * 4 + chunkp]);
#pragma unroll
    for (int i = 0; i < 4; ++i)
#pragma unroll
      for (int j = 0; j < 4; ++j)
        acc[i][j] = __builtin_amdgcn_mfma_f32_16x16x32_bf16(a[i], b[j], acc[i][j], 0, 0, 0);
    __syncthreads();
  }
#undef STAGE

#pragma unroll
  for (int i = 0; i < 4; ++i) {
    int mrow = bm + wr * 64 + i * 16 + (l >> 4) * 4;
#pragma unroll
    for (int j = 0; j < 4; ++j) {
      int ncol = bn + wc * 64 + j * 16 + (l & 15);
      if (MODE == 0) {
        float bv = bias[ncol];
#pragma unroll
        for (int r = 0; r < 4; ++r)
          Cb[(size_t)(mrow + r) * 8192 + ncol] = f2bf_rne(acc[i][j][r] + bv);
      } else {
        ushort_t* P = Cb + (size_t)blockIdx.z * (4096u * 1024u);
#pragma unroll
        for (int r = 0; r < 4; ++r)
          P[(size_t)(mrow + r) * 1024 + ncol] = f2bf_rne(acc[i][j][r]);
      }
    }
  }
}

// proj row layout (8192 bf16): [0:1024) psi_re | [1024:2048) psi_im |
// [2048:3072) phi_re | [3072:4096) phi_im | [4096..) bs | ps | btx | ptx

// ---------------- U_scout = gate * B(bs,ps) * psi ----------------
__global__ __launch_bounds__(256) void u_scout(
    const float* __restrict__ gate, const ushort_t* __restrict__ proj,
    float2* __restrict__ U) {
  int idx = blockIdx.x * 256 + threadIdx.x;
  int m = idx >> 10, s = idx & (SDN - 1);
  const ushort_t* pr = proj + ((size_t)m << 13);
  float g  = gate[m];
  float bv = softplusf_(bf2f(pr[4096 + s]));
  float ph = PI_F * tanhf(bf2f(pr[5120 + s]));
  float sph, cph;
  sincosf(ph, &sph, &cph);
  float br = bv * cph, bi = bv * sph;
  float pre = bf2f(pr[s]), pim = bf2f(pr[1024 + s]);
  U[idx] = make_float2(g * (br * pre - bi * pim), g * (br * pim + bi * pre));
}

// ---------------- U_true = gate * B(btx+P0+P1+b_bth, ptx) * psi ----------------
__global__ __launch_bounds__(256) void u_true(
    const float* __restrict__ gate, const ushort_t* __restrict__ proj,
    const ushort_t* __restrict__ P0, const ushort_t* __restrict__ P1,
    const float* __restrict__ b_bth, float2* __restrict__ U) {
  int idx = blockIdx.x * 256 + threadIdx.x;
  int m = idx >> 10, s = idx & (SDN - 1);
  const ushort_t* pr = proj + ((size_t)m << 13);
  float g  = gate[m];
  float blv = bf2f(pr[6144 + s]) + bf2f(P0[idx]) + bf2f(P1[idx]) + b_bth[s];
  float bv = softplusf_(blv);
  float ph = PI_F * tanhf(bf2f(pr[7168 + s]));
  float sph, cph;
  sincosf(ph, &sph, &cph);
  float br = bv * cph, bi = bv * sph;
  float pre = bf2f(pr[s]), pim = bf2f(pr[1024 + s]);
  U[idx] = make_float2(g * (br * pre - bi * pim), g * (br * pim + bi * pre));
}

// ---------------- chunked parallel scan ----------------
__global__ __launch_bounds__(256) void scan_stage1(
    const float2* __restrict__ U, const float2* __restrict__ a,
    float2* __restrict__ carry) {
  int s = blockIdx.x * 256 + threadIdx.x;
  int c = blockIdx.y, b = blockIdx.z;
  float2 av = a[s];
  float2 V = make_float2(0.f, 0.f);
  const float2* Up = U + (size_t)(b * LSEQ + c * LCHUNK) * SDN + s;
#pragma unroll 4
  for (int t = 0; t < LCHUNK; ++t)
    V = cfma2(av, V, Up[(size_t)t * SDN]);
  carry[(size_t)(b * NCHUNK + c) * SDN + s] = V;
}

__global__ __launch_bounds__(256) void scan_stage2(
    const float2* __restrict__ carry, const float2* __restrict__ A,
    float2* __restrict__ prefix) {
  int s = blockIdx.x * 256 + threadIdx.x;
  int b = blockIdx.z;
  float2 Av = A[s];
  float2 P = make_float2(0.f, 0.f);
  for (int c = 0; c < NCHUNK; ++c) {
    size_t off = (size_t)(b * NCHUNK + c) * SDN + s;
    prefix[off] = P;
    P = cfma2(Av, P, carry[off]);
  }
}

// in-place: Vout may alias U (read-then-write per element)
__global__ __launch_bounds__(256) void scan_stage3(
    const float2* __restrict__ U, const float2* __restrict__ a,
    const float2* __restrict__ prefix, float2* __restrict__ Vout) {
  int s = blockIdx.x * 256 + threadIdx.x;
  int c = blockIdx.y, b = blockIdx.z;
  float2 av = a[s];
  float2 V = prefix[(size_t)(b * NCHUNK + c) * SDN + s];
  size_t base = (size_t)(b * LSEQ + c * LCHUNK) * SDN + s;
#pragma unroll 4
  for (int t = 0; t < LCHUNK; ++t) {
    V = cfma2(av, V, U[base + (size_t)t * SDN]);
    Vout[base + (size_t)t * SDN] = V;
  }
}

// ---------------- H_flat (bf16): shifted, RMS-normalized scout state ----------------
__global__ __launch_bounds__(256) void hflat_kernel(
    const float2* __restrict__ V, ushort_t* __restrict__ Hflat) {
  int m = blockIdx.x;
  int t = m & (LSEQ - 1);
  float2 v[4];
  float sum = 0.f;
#pragma unroll
  for (int i = 0; i < 4; ++i) {
    int s = threadIdx.x + i * 256;
    float2 vv = make_float2(0.f, 0.f);
    if (t > 0) vv = V[(size_t)(m - 1) * SDN + s];
    v[i] = vv;
    sum += vv.x * vv.x + vv.y * vv.y;
  }
  __shared__ float red[256];
  red[threadIdx.x] = sum;
  __syncthreads();
  for (int o = 128; o > 0; o >>= 1) {
    if (threadIdx.x < o) red[threadIdx.x] += red[threadIdx.x + o];
    __syncthreads();
  }
  float inv = 1.0f / sqrtf(red[0] * (1.f / SDN) + 1e-6f);
  ushort_t* hr = Hflat + ((size_t)m << 11);
#pragma unroll
  for (int i = 0; i < 4; ++i) {
    int s = threadIdx.x + i * 256;
    hr[s] = f2bf_rne(v[i].x * inv);
    hr[SDN + s] = f2bf_rne(v[i].y * inv);
  }
}

// ---------------- simpson + RMS + MIMO + conj(phi) + tau/beta ----------------
__global__ __launch_bounds__(256) void final_kernel(
    const float2* __restrict__ V, const ushort_t* __restrict__ proj,
    const float* __restrict__ mimo, const float* __restrict__ tau,
    const float* __restrict__ beta, float* __restrict__ out) {
  int bid = blockIdx.x;
  int m = ((bid & 7) << 9) | (bid >> 3);  // XCD-local consecutive m for V L2 reuse
  int t = m & (LSEQ - 1);
  __shared__ float2 hl[SDN];
  __shared__ float red[256];
  float sum = 0.f;
#pragma unroll
  for (int i = 0; i < 4; ++i) {
    int s = threadIdx.x + i * 256;
    float2 v0 = V[(size_t)m * SDN + s];
    float2 v1 = make_float2(0.f, 0.f), v2 = make_float2(0.f, 0.f);
    if (t >= 1) v1 = V[(size_t)(m - 1) * SDN + s];
    if (t >= 2) v2 = V[(size_t)(m - 2) * SDN + s];
    float2 h = make_float2((v0.x + 4.f * v1.x + v2.x) * (1.f / 6.f),
                           (v0.y + 4.f * v1.y + v2.y) * (1.f / 6.f));
    hl[s] = h;
    sum += h.x * h.x + h.y * h.y;
  }
  red[threadIdx.x] = sum;
  __syncthreads();
  for (int o = 128; o > 0; o >>= 1) {
    if (threadIdx.x < o) red[threadIdx.x] += red[threadIdx.x + o];
    __syncthreads();
  }
  float inv = 1.0f / sqrtf(red[0] * (1.f / SDN) + 1e-6f);
  float tv = tau[0], bv = beta[0];
  const ushort_t* pp = proj + ((size_t)m << 13) + 2048;  // phi columns
#pragma unroll
  for (int i = 0; i < 4; ++i) {
    int s = threadIdx.x + i * 256;
    int g = s >> 3, q = s & 7;
    const float* wp = mimo + (size_t)g * 64 + q;
    float hr = 0.f, hi = 0.f;
#pragma unroll
    for (int p = 0; p < 8; ++p) {
      float wv = wp[p * 8];
      float2 hp = hl[(g << 3) + p];
      hr = fmaf(hp.x, wv, hr);
      hi = fmaf(hp.y, wv, hi);
    }
    hr *= inv; hi *= inv;
    float o1 = hr * bf2f(pp[s]) + hi * bf2f(pp[SDN + s]);
    out[(size_t)m * SDN + s] = tv * o1 + bv;
  }
}

extern "C" void kernel_launch(void* const* d_in, const int* in_sizes, int n_in,
                              void* d_out, int out_size, void* d_ws, size_t ws_size,
                              hipStream_t stream) {
  const float* x      = (const float*)d_in[0];
  const float* z_prev = (const float*)d_in[1];
  const float* W_psi  = (const float*)d_in[2];
  const float* b_psi  = (const float*)d_in[3];
  const float* W_phi  = (const float*)d_in[4];
  const float* b_phi  = (const float*)d_in[5];
  const float* W_gate = (const float*)d_in[6];
  const float* b_gate = (const float*)d_in[7];
  const float* s_gain = (const float*)d_in[8];
  const float* omega  = (const float*)d_in[9];
  const float* log_g  = (const float*)d_in[10];
  const float* dt     = (const float*)d_in[11];
  const float* W_bs   = (const float*)d_in[12];
  const float* b_bs   = (const float*)d_in[13];
  const float* W_ps   = (const float*)d_in[14];
  const float* b_ps   = (const float*)d_in[15];
  const float* W_btx  = (const float*)d_in[16];
  const float* b_btx  = (const float*)d_in[17];
  const float* W_bth  = (const float*)d_in[18];
  const float* b_bth  = (const float*)d_in[19];
  const float* W_ptx  = (const float*)d_in[20];
  const float* b_ptx  = (const float*)d_in[21];
  const float* mimo_w = (const float*)d_in[22];
  const float* tau    = (const float*)d_in[23];
  const float* beta   = (const float*)d_in[24];
  float* out = (float*)d_out;

  float* ws = (float*)d_ws;
  const size_t M1 = 1 << 20;
  // ---- workspace layout, float units (explicit byte accounting) ----
  // [0,16M)   proj   : 32M bf16 = [4096][8192]  (psi|phi|bs|ps|btx|ptx)
  // [16M,24M) U/V    : 4M float2 (scan in-place)
  // [24M,26M) xb     : 4M bf16
  // [26M,30M) wcat   : 8M bf16 [8192][1024]; P0/P1 alias after fused GEMM
  // [30M,31M) wbthb  : 2M bf16 [1024][2048]
  // [31M,35M) hflatB : 8M bf16 [4096][2048]
  // [35M,..)  bcat(8192) gate(4096) ac(2048) Ac(2048) carry(128K) prefix(128K)
  ushort_t* proj   = (ushort_t*)ws;
  float2*   U      = (float2*)(ws + 16 * M1);
  float2*   V      = U;
  ushort_t* xb     = (ushort_t*)(ws + 24 * M1);
  ushort_t* wcat   = (ushort_t*)(ws + 26 * M1);
  ushort_t* P0     = wcat;
  ushort_t* P1     = wcat + 4u * 1024u * 1024u;
  ushort_t* wbthb  = (ushort_t*)(ws + 30 * M1);
  ushort_t* hflatB = (ushort_t*)(ws + 31 * M1);
  float*    bcat   = ws + 35 * M1;
  float*    gate   = bcat + 8192;
  float2*   ac     = (float2*)(gate + 4096);
  float2*   Ac     = ac + 1024;
  float2*   carry  = Ac + 1024;
  float2*   prefix = carry + 65536;
  (void)ws_size; (void)in_sizes; (void)n_in; (void)out_size;

  dim3 blk(256);

  // coefficients + gate + conversions
  coef_kernel<<<dim3(4), blk, 0, stream>>>(omega, log_g, dt, ac, Ac);
  gate_kernel<<<dim3(BLROWS / 4), blk, 0, stream>>>(x, z_prev, W_gate, b_gate, s_gain, gate);
  f2bf_kernel<<<dim3(4096), blk, 0, stream>>>(x, xb);
  f2bf_kernel<<<dim3(2048), blk, 0, stream>>>(W_psi, wcat);
  f2bf_kernel<<<dim3(2048), blk, 0, stream>>>(W_phi, wcat + 2097152u);
  f2bf_kernel<<<dim3(1024), blk, 0, stream>>>(W_bs,  wcat + 4194304u);
  f2bf_kernel<<<dim3(1024), blk, 0, stream>>>(W_ps,  wcat + 5242880u);
  f2bf_kernel<<<dim3(1024), blk, 0, stream>>>(W_btx, wcat + 6291456u);
  f2bf_kernel<<<dim3(1024), blk, 0, stream>>>(W_ptx, wcat + 7340032u);
  f2bf_kernel<<<dim3(2048), blk, 0, stream>>>(W_bth, wbthb);
  bcat_kernel<<<dim3(32), blk, 0, stream>>>(b_psi, b_phi, b_bs, b_ps, b_btx, b_ptx, bcat);

  // fused projection GEMM: [4096,1024] @ [8192,1024]^T -> proj (bf16)
  gemm_bf16<0><<<dim3(2048), blk, 0, stream>>>(xb, wcat, bcat, proj);

  // U_scout, scan 1
  u_scout<<<dim3(BLROWS * SDN / 256), blk, 0, stream>>>(gate, proj, U);
  scan_stage1<<<dim3(SDN / 256, NCHUNK, BATCHN), blk, 0, stream>>>(U, ac, carry);
  scan_stage2<<<dim3(SDN / 256, 1, BATCHN), blk, 0, stream>>>(carry, Ac, prefix);
  scan_stage3<<<dim3(SDN / 256, NCHUNK, BATCHN), blk, 0, stream>>>(U, ac, prefix, V);

  // H_flat (bf16), split-K bth GEMM -> bf16 partials (into dead wcat)
  hflat_kernel<<<dim3(BLROWS), blk, 0, stream>>>(V, hflatB);
  gemm_bf16<1><<<dim3(8, 32, 2), blk, 0, stream>>>(hflatB, wbthb, bcat, P0);

  // U_true, scan 2
  u_true<<<dim3(BLROWS * SDN / 256), blk, 0, stream>>>(gate, proj, P0, P1, b_bth, U);
  scan_stage1<<<dim3(SDN / 256, NCHUNK, BATCHN), blk, 0, stream>>>(U, ac, carry);
  scan_stage2<<<dim3(SDN / 256, 1, BATCHN), blk, 0, stream>>>(carry, Ac, prefix);
  scan_stage3<<<dim3(SDN / 256, NCHUNK, BATCHN), blk, 0, stream>>>(U, ac, prefix, V);

  // fused epilogue
  final_kernel<<<dim3(BLROWS), blk, 0, stream>>>(V, proj, mimo_w, tau, beta, out);
}